// Round 1
// baseline (2157.291 us; speedup 1.0000x reference)
//
#include <hip/hip_runtime.h>
#include <math.h>

#define F 64
#define SE 20   // LDS row stride: 16 edges + 4 pad floats; 80B = 16B-aligned

__device__ __forceinline__ void ld4(const float* p, float o[4]) {
  float4 v = *(const float4*)p;
  o[0] = v.x; o[1] = v.y; o[2] = v.z; o[3] = v.w;
}

__device__ __forceinline__ float silu_f(float x) { return x / (1.0f + expf(-x)); }

// acc[4][4] += A_lds[k][e0..e0+3] (x) W[k][f0..f0+3], k = 0..63
__device__ __forceinline__ void gemm64(const float* lb, const float* __restrict__ W,
                                       int f0, int e0, float acc[4][4]) {
  #pragma unroll 4
  for (int k = 0; k < F; ++k) {
    float a[4]; ld4(lb + k * SE + e0, a);
    float w[4]; ld4(W + k * F + f0, w);
    #pragma unroll
    for (int i = 0; i < 4; ++i)
      #pragma unroll
      for (int j = 0; j < 4; ++j)
        acc[i][j] = fmaf(a[i], w[j], acc[i][j]);
  }
}

__global__ __launch_bounds__(256, 2) void edge_kernel(
    const float* __restrict__ node_s, const float* __restrict__ node_v,
    const float* __restrict__ edge_s, const float* __restrict__ edge_v,
    const float* __restrict__ dist,   const float* __restrict__ vctr,
    const int* __restrict__ src,      const int* __restrict__ dst,
    const float* __restrict__ W_nn, const float* __restrict__ b_nn,
    const float* __restrict__ W_ep, const float* __restrict__ b_ep,
    const float* __restrict__ W_g1, const float* __restrict__ b_g1,
    const float* __restrict__ W_g2, const float* __restrict__ b_g2,
    const float* __restrict__ W_ev, const float* __restrict__ b_ev,
    float* __restrict__ es_out, float* __restrict__ ev_out,
    float* __restrict__ nes_acc, float* __restrict__ nev_acc, float* __restrict__ deg,
    int E, int n_tiles)
{
  __shared__ __align__(16) float lds[4 * 3 * F * SE]; // 61440B -> 2 blocks/CU
  const int wid  = threadIdx.x >> 6;
  const int lane = threadIdx.x & 63;
  const int tile = blockIdx.x * 4 + wid;
  if (tile >= n_tiles) return;
  const int fl = lane & 15, el = lane >> 4;
  const int f0 = fl * 4, e0 = el * 4;
  const int ebase = tile * 16;

  float* B1 = &lds[wid * 3 * F * SE];
  float* B2 = B1 + F * SE;
  float* B3 = B2 + F * SE;

  // ---- stage node_s[src], node_s[dst], edge_s TRANSPOSED [k][e] ----
  #pragma unroll 4
  for (int le = 0; le < 16; ++le) {
    int e = ebase + le; if (e >= E) e = E - 1;
    int s = src[e], d = dst[e];
    B1[lane * SE + le] = node_s[s * F + lane];
    B2[lane * SE + le] = node_s[d * F + lane];
    B3[lane * SE + le] = edge_s[e * F + lane];
  }
  __builtin_amdgcn_wave_barrier();

  // ---- ep = edge_s @ W_ep + b_ep ; nn = [src|dst] @ W_nn + b_nn ----
  float accP[4][4] = {};
  gemm64(B3, W_ep, f0, e0, accP);
  float accN[4][4] = {};
  gemm64(B1, W_nn,          f0, e0, accN);
  gemm64(B2, W_nn + 64 * F, f0, e0, accN);
  float bnn[4]; ld4(b_nn + f0, bnn);
  float bep[4]; ld4(b_ep + f0, bep);

  // em = nn * ep -> write transposed into B1
  #pragma unroll
  for (int j = 0; j < 4; ++j) {
    float4 v;
    v.x = (accN[0][j] + bnn[j]) * (accP[0][j] + bep[j]);
    v.y = (accN[1][j] + bnn[j]) * (accP[1][j] + bep[j]);
    v.z = (accN[2][j] + bnn[j]) * (accP[2][j] + bep[j]);
    v.w = (accN[3][j] + bnn[j]) * (accP[3][j] + bep[j]);
    *(float4*)(B1 + (f0 + j) * SE + e0) = v;
  }
  __builtin_amdgcn_wave_barrier();

  // h = silu(em @ W_g1 + b_g1) -> transposed into B2
  float accH[4][4] = {};
  gemm64(B1, W_g1, f0, e0, accH);
  float bg1[4]; ld4(b_g1 + f0, bg1);
  #pragma unroll
  for (int j = 0; j < 4; ++j) {
    float4 v;
    v.x = silu_f(accH[0][j] + bg1[j]);
    v.y = silu_f(accH[1][j] + bg1[j]);
    v.z = silu_f(accH[2][j] + bg1[j]);
    v.w = silu_f(accH[3][j] + bg1[j]);
    *(float4*)(B2 + (f0 + j) * SE + e0) = v;
  }
  __builtin_amdgcn_wave_barrier();

  // es_upd = (h @ W_g2 + b_g2) * c
  float accS[4][4] = {};
  gemm64(B2, W_g2, f0, e0, accS);
  float bg2[4]; ld4(b_g2 + f0, bg2);
  float cc[4];
  #pragma unroll
  for (int i = 0; i < 4; ++i) {
    int e = ebase + e0 + i; if (e >= E) e = E - 1;
    float d = dist[e];
    cc[i] = (d < 5.0f) ? 0.5f * (cosf(3.14159265358979f * d * 0.2f) + 1.0f) : 0.0f;
  }
  #pragma unroll
  for (int i = 0; i < 4; ++i)
    #pragma unroll
    for (int j = 0; j < 4; ++j)
      accS[i][j] = (accS[i][j] + bg2[j]) * cc[i];

  // edge_s_out = es_upd + edge_s (edge_s still transposed in B3); atomics into nes_acc
  #pragma unroll
  for (int i = 0; i < 4; ++i) {
    int e = ebase + e0 + i;
    if (e < E) {
      float4 o;
      o.x = accS[i][0] + B3[(f0 + 0) * SE + e0 + i];
      o.y = accS[i][1] + B3[(f0 + 1) * SE + e0 + i];
      o.z = accS[i][2] + B3[(f0 + 2) * SE + e0 + i];
      o.w = accS[i][3] + B3[(f0 + 3) * SE + e0 + i];
      *(float4*)(es_out + (size_t)e * F + f0) = o;
      int dn = dst[e];
      #pragma unroll
      for (int j = 0; j < 4; ++j)
        atomicAdd(&nes_acc[dn * F + f0 + j], accS[i][j]);
    }
  }

  // write es_upd transposed into B3 (reads above already done, wave in-order)
  #pragma unroll
  for (int j = 0; j < 4; ++j) {
    float4 v;
    v.x = accS[0][j]; v.y = accS[1][j]; v.z = accS[2][j]; v.w = accS[3][j];
    *(float4*)(B3 + (f0 + j) * SE + e0) = v;
  }
  __builtin_amdgcn_wave_barrier();

  // vch = es_upd @ W_ev + b_ev  (three thirds: nch, ech, rch)
  float vc[3][4][4] = {};
  #pragma unroll 2
  for (int k = 0; k < F; ++k) {
    float a[4]; ld4(B3 + k * SE + e0, a);
    float w0[4], w1[4], w2[4];
    ld4(W_ev + k * 192 + f0, w0);
    ld4(W_ev + k * 192 + 64 + f0, w1);
    ld4(W_ev + k * 192 + 128 + f0, w2);
    #pragma unroll
    for (int i = 0; i < 4; ++i)
      #pragma unroll
      for (int j = 0; j < 4; ++j) {
        vc[0][i][j] = fmaf(a[i], w0[j], vc[0][i][j]);
        vc[1][i][j] = fmaf(a[i], w1[j], vc[1][i][j]);
        vc[2][i][j] = fmaf(a[i], w2[j], vc[2][i][j]);
      }
  }
  {
    float be0[4], be1[4], be2[4];
    ld4(b_ev + f0, be0); ld4(b_ev + 64 + f0, be1); ld4(b_ev + 128 + f0, be2);
    #pragma unroll
    for (int i = 0; i < 4; ++i)
      #pragma unroll
      for (int j = 0; j < 4; ++j) {
        vc[0][i][j] += be0[j]; vc[1][i][j] += be1[j]; vc[2][i][j] += be2[j];
      }
  }

  // ev_upd = (node_v[src]*nch + edge_v*ech + vctr*rch) * c ; outputs + atomics
  #pragma unroll
  for (int i = 0; i < 4; ++i) {
    int e = ebase + e0 + i;
    if (e >= E) continue;
    int s = src[e], dn = dst[e];
    #pragma unroll
    for (int dd = 0; dd < 3; ++dd) {
      float nv[4]; ld4(node_v + (size_t)s * 192 + dd * 64 + f0, nv);
      float ev[4]; ld4(edge_v + (size_t)e * 192 + dd * 64 + f0, ev);
      float vn = vctr[e * 3 + dd];
      float4 o;
      float evu[4];
      #pragma unroll
      for (int j = 0; j < 4; ++j)
        evu[j] = (nv[j] * vc[0][i][j] + ev[j] * vc[1][i][j] + vn * vc[2][i][j]) * cc[i];
      o.x = evu[0] + ev[0]; o.y = evu[1] + ev[1]; o.z = evu[2] + ev[2]; o.w = evu[3] + ev[3];
      *(float4*)(ev_out + (size_t)e * 192 + dd * 64 + f0) = o;
      #pragma unroll
      for (int j = 0; j < 4; ++j)
        atomicAdd(&nev_acc[dn * 192 + dd * 64 + f0 + j], evu[j]);
    }
  }
  if (fl == 0) {
    #pragma unroll
    for (int i = 0; i < 4; ++i) {
      int e = ebase + e0 + i;
      if (e < E) atomicAdd(&deg[dst[e]], 1.0f);
    }
  }
}

__global__ __launch_bounds__(256) void node_kernel(
    const float* __restrict__ node_s, const float* __restrict__ node_v,
    const float* __restrict__ nes_acc, const float* __restrict__ nev_acc,
    const float* __restrict__ deg,
    const float* __restrict__ W_nvout,
    const float* __restrict__ W_nvc, const float* __restrict__ b_nvc,
    const float* __restrict__ W_nvp,
    const float* __restrict__ W_nsp, const float* __restrict__ b_nsp,
    const float* __restrict__ ln_g, const float* __restrict__ ln_b,
    const float* __restrict__ cn_s,
    float* __restrict__ ns_out, float* __restrict__ nv_out, int N)
{
  __shared__ __align__(16) float scm[4 * 8 * 68];
  const int wid = threadIdx.x >> 6, lane = threadIdx.x & 63;
  const int n = blockIdx.x * 4 + wid;
  if (n >= N) return;
  float* S = &scm[wid * 8 * 68];

  const float inv = 1.0f / fmaxf(deg[n], 1.0f);
  float nes = nes_acc[n * 64 + lane] * inv;
  float nev[3];
  #pragma unroll
  for (int dd = 0; dd < 3; ++dd) nev[dd] = nev_acc[n * 192 + dd * 64 + lane] * inv;
  S[0 * 68 + lane] = nev[0]; S[1 * 68 + lane] = nev[1];
  S[2 * 68 + lane] = nev[2]; S[3 * 68 + lane] = nes;
  __builtin_amdgcn_wave_barrier();

  // n_ev @ W_nvout -> o1,o2,o3  (each [3][f])
  float o1[3] = {}, o2[3] = {}, o3[3] = {};
  for (int k = 0; k < 64; k += 4) {
    float a0[4], a1[4], a2[4];
    ld4(S + 0 * 68 + k, a0); ld4(S + 1 * 68 + k, a1); ld4(S + 2 * 68 + k, a2);
    #pragma unroll
    for (int kk = 0; kk < 4; ++kk) {
      float w0 = W_nvout[(k + kk) * 192 + lane];
      float w1 = W_nvout[(k + kk) * 192 + 64 + lane];
      float w2 = W_nvout[(k + kk) * 192 + 128 + lane];
      o1[0] = fmaf(a0[kk], w0, o1[0]); o1[1] = fmaf(a1[kk], w0, o1[1]); o1[2] = fmaf(a2[kk], w0, o1[2]);
      o2[0] = fmaf(a0[kk], w1, o2[0]); o2[1] = fmaf(a1[kk], w1, o2[1]); o2[2] = fmaf(a2[kk], w1, o2[2]);
      o3[0] = fmaf(a0[kk], w2, o3[0]); o3[1] = fmaf(a1[kk], w2, o3[1]); o3[2] = fmaf(a2[kk], w2, o3[2]);
    }
  }
  float nrm = sqrtf(o3[0] * o3[0] + o3[1] * o3[1] + o3[2] * o3[2]);
  S[4 * 68 + lane] = nrm;
  __builtin_amdgcn_wave_barrier();

  // v_channel = [n_es | ||o3||] @ W_nvc + b_nvc
  float vch = 0.0f;
  for (int k = 0; k < 64; k += 4) {
    float a[4], b[4];
    ld4(S + 3 * 68 + k, a); ld4(S + 4 * 68 + k, b);
    #pragma unroll
    for (int kk = 0; kk < 4; ++kk) {
      vch = fmaf(a[kk], W_nvc[(k + kk) * 64 + lane], vch);
      vch = fmaf(b[kk], W_nvc[(64 + k + kk) * 64 + lane], vch);
    }
  }
  vch += b_nvc[lane];

  float nvu[3];
  #pragma unroll
  for (int dd = 0; dd < 3; ++dd) {
    nvu[dd] = o1[dd] * vch + o2[dd];
    S[(5 + dd) * 68 + lane] = nvu[dd];
  }
  __builtin_amdgcn_wave_barrier();

  // nvp1/nvp2 = nv_upd @ W_nvp (split)
  float p1[3] = {}, p2[3] = {};
  for (int k = 0; k < 64; k += 4) {
    float a0[4], a1[4], a2[4];
    ld4(S + 5 * 68 + k, a0); ld4(S + 6 * 68 + k, a1); ld4(S + 7 * 68 + k, a2);
    #pragma unroll
    for (int kk = 0; kk < 4; ++kk) {
      float w1 = W_nvp[(k + kk) * 128 + lane];
      float w2 = W_nvp[(k + kk) * 128 + 64 + lane];
      p1[0] = fmaf(a0[kk], w1, p1[0]); p1[1] = fmaf(a1[kk], w1, p1[1]); p1[2] = fmaf(a2[kk], w1, p1[2]);
      p2[0] = fmaf(a0[kk], w2, p2[0]); p2[1] = fmaf(a1[kk], w2, p2[1]); p2[2] = fmaf(a2[kk], w2, p2[2]);
    }
  }

  // ns1/ns2 = silu(n_es @ W_nsp + b_nsp) split
  float s1a = 0.0f, s2a = 0.0f;
  for (int k = 0; k < 64; k += 4) {
    float a[4];
    ld4(S + 3 * 68 + k, a);
    #pragma unroll
    for (int kk = 0; kk < 4; ++kk) {
      s1a = fmaf(a[kk], W_nsp[(k + kk) * 128 + lane], s1a);
      s2a = fmaf(a[kk], W_nsp[(k + kk) * 128 + 64 + lane], s2a);
    }
  }
  float s1 = silu_f(s1a + b_nsp[lane]);
  float s2 = silu_f(s2a + b_nsp[64 + lane]);

  float nvdot = p1[0] * p2[0] + p1[1] * p2[1] + p1[2] * p2[2];
  float nsu = nvdot * s1 + s2;

  // LayerNorm over 64 features (wave-wide)
  float xs = nsu + node_s[n * 64 + lane];
  float sum = xs, sumsq = xs * xs;
  #pragma unroll
  for (int o = 32; o; o >>= 1) {
    sum += __shfl_xor(sum, o);
    sumsq += __shfl_xor(sumsq, o);
  }
  float mu = sum * (1.0f / 64.0f);
  float var = sumsq * (1.0f / 64.0f) - mu * mu;
  ns_out[n * 64 + lane] = (xs - mu) * rsqrtf(var + 1e-5f) * ln_g[lane] + ln_b[lane];

  // CoorsNorm over 3D axis (lane-local)
  float vv[3];
  #pragma unroll
  for (int dd = 0; dd < 3; ++dd) vv[dd] = nvu[dd] + node_v[n * 192 + dd * 64 + lane];
  float vn2 = sqrtf(vv[0] * vv[0] + vv[1] * vv[1] + vv[2] * vv[2]);
  float scale = cn_s[lane] / fmaxf(vn2, 1e-8f);
  #pragma unroll
  for (int dd = 0; dd < 3; ++dd)
    nv_out[n * 192 + dd * 64 + lane] = vv[dd] * scale;
}

extern "C" void kernel_launch(void* const* d_in, const int* in_sizes, int n_in,
                              void* d_out, int out_size, void* d_ws, size_t ws_size,
                              hipStream_t stream) {
  const float* node_s = (const float*)d_in[0];
  const float* node_v = (const float*)d_in[1];
  const float* edge_s = (const float*)d_in[2];
  const float* edge_v = (const float*)d_in[3];
  const float* dist   = (const float*)d_in[4];
  const float* vctr   = (const float*)d_in[5];
  const int*   src    = (const int*)d_in[6];
  const int*   dst    = (const int*)d_in[7];
  const float* W_nn = (const float*)d_in[8];  const float* b_nn = (const float*)d_in[9];
  const float* W_ep = (const float*)d_in[10]; const float* b_ep = (const float*)d_in[11];
  const float* W_g1 = (const float*)d_in[12]; const float* b_g1 = (const float*)d_in[13];
  const float* W_g2 = (const float*)d_in[14]; const float* b_g2 = (const float*)d_in[15];
  const float* W_ev = (const float*)d_in[16]; const float* b_ev = (const float*)d_in[17];
  const float* W_nvout = (const float*)d_in[18];
  const float* W_nvc = (const float*)d_in[19]; const float* b_nvc = (const float*)d_in[20];
  const float* W_nvp = (const float*)d_in[21];
  const float* W_nsp = (const float*)d_in[22]; const float* b_nsp = (const float*)d_in[23];
  const float* ln_g = (const float*)d_in[24]; const float* ln_b = (const float*)d_in[25];
  const float* cn_s = (const float*)d_in[26];

  const int N = in_sizes[0] / 64;
  const int E = in_sizes[2] / 64;

  float* out    = (float*)d_out;
  float* ns_out = out;
  float* nv_out = out + (size_t)N * 64;
  float* es_out = out + (size_t)N * 256;
  float* ev_out = out + (size_t)N * 256 + (size_t)E * 64;

  float* nes_acc = (float*)d_ws;
  float* nev_acc = nes_acc + (size_t)N * 64;
  float* degp    = nev_acc + (size_t)N * 192;

  hipMemsetAsync(d_ws, 0, (size_t)N * 257 * sizeof(float), stream);

  int n_tiles = (E + 15) / 16;
  edge_kernel<<<(n_tiles + 3) / 4, 256, 0, stream>>>(
      node_s, node_v, edge_s, edge_v, dist, vctr, src, dst,
      W_nn, b_nn, W_ep, b_ep, W_g1, b_g1, W_g2, b_g2, W_ev, b_ev,
      es_out, ev_out, nes_acc, nev_acc, degp, E, n_tiles);

  node_kernel<<<(N + 3) / 4, 256, 0, stream>>>(
      node_s, node_v, nes_acc, nev_acc, degp,
      W_nvout, W_nvc, b_nvc, W_nvp, W_nsp, b_nsp,
      ln_g, ln_b, cn_s, ns_out, nv_out, N);
}

// Round 2
// 1236.595 us; speedup vs baseline: 1.7445x; 1.7445x over previous
//
#include <hip/hip_runtime.h>
#include <math.h>

#define F 64
#define SE 20   // LDS row stride: 16 edges + 4 pad floats; 80B = 16B-aligned

__device__ __forceinline__ void ld4(const float* p, float o[4]) {
  float4 v = *(const float4*)p;
  o[0] = v.x; o[1] = v.y; o[2] = v.z; o[3] = v.w;
}

__device__ __forceinline__ float silu_f(float x) { return x / (1.0f + expf(-x)); }

// acc[4][4] += A_lds[k][e0..e0+3] (x) W[k][f0..f0+3], k = 0..63
__device__ __forceinline__ void gemm64(const float* lb, const float* __restrict__ W,
                                       int f0, int e0, float acc[4][4]) {
  #pragma unroll 4
  for (int k = 0; k < F; ++k) {
    float a[4]; ld4(lb + k * SE + e0, a);
    float w[4]; ld4(W + k * F + f0, w);
    #pragma unroll
    for (int i = 0; i < 4; ++i)
      #pragma unroll
      for (int j = 0; j < 4; ++j)
        acc[i][j] = fmaf(a[i], w[j], acc[i][j]);
  }
}

// ============ CSR build ============
__global__ void hist_kernel(const int* __restrict__ dst, int* __restrict__ cnt, int E) {
  int i = blockIdx.x * blockDim.x + threadIdx.x;
  if (i < E) atomicAdd(&cnt[dst[i]], 1);
}

__global__ __launch_bounds__(1024) void scan_kernel(int* __restrict__ cnt,
                                                    int* __restrict__ rowstart, int N) {
  __shared__ int wsum[16];
  const int tid = threadIdx.x;
  const int wv = tid >> 6;
  int carry = 0;
  for (int base = 0; base < N; base += 1024) {
    int i = base + tid;
    int v = (i < N) ? cnt[i] : 0;
    int x = v;
    #pragma unroll
    for (int o = 1; o < 64; o <<= 1) {
      int y = __shfl_up(x, o);
      if ((tid & 63) >= o) x += y;
    }
    if ((tid & 63) == 63) wsum[wv] = x;
    __syncthreads();
    if (tid < 16) {
      int s = wsum[tid];
      #pragma unroll
      for (int o = 1; o < 16; o <<= 1) {
        int y = __shfl_up(s, o);
        if (tid >= o) s += y;
      }
      wsum[tid] = s;
    }
    __syncthreads();
    int woff = (wv > 0) ? wsum[wv - 1] : 0;
    if (i < N) {
      int excl = carry + woff + x - v;
      rowstart[i] = excl;
      cnt[i] = excl;          // cnt becomes the scatter cursor
    }
    carry += wsum[15];
    __syncthreads();
  }
  if (tid == 0) rowstart[N] = carry;
}

__global__ void scatter_kernel(const int* __restrict__ dst, int* __restrict__ cursor,
                               int* __restrict__ elist, int E) {
  int i = blockIdx.x * blockDim.x + threadIdx.x;
  if (i < E) {
    int pos = atomicAdd(&cursor[dst[i]], 1);
    elist[pos] = i;
  }
}

// ============ edge kernel (no atomics, 2 LDS buffers) ============
__global__ __launch_bounds__(256, 4) void edge_kernel(
    const float* __restrict__ node_s, const float* __restrict__ node_v,
    const float* __restrict__ edge_s, const float* __restrict__ edge_v,
    const float* __restrict__ dist,   const float* __restrict__ vctr,
    const int* __restrict__ src,      const int* __restrict__ dst,
    const float* __restrict__ W_nn, const float* __restrict__ b_nn,
    const float* __restrict__ W_ep, const float* __restrict__ b_ep,
    const float* __restrict__ W_g1, const float* __restrict__ b_g1,
    const float* __restrict__ W_g2, const float* __restrict__ b_g2,
    const float* __restrict__ W_ev, const float* __restrict__ b_ev,
    float* __restrict__ es_out, float* __restrict__ ev_out,
    int E, int n_tiles)
{
  __shared__ __align__(16) float lds[4 * 2 * F * SE]; // 40960B -> 4 blocks/CU
  const int wid  = threadIdx.x >> 6;
  const int lane = threadIdx.x & 63;
  const int tile = blockIdx.x * 4 + wid;
  if (tile >= n_tiles) return;
  const int fl = lane & 15, el = lane >> 4;
  const int f0 = fl * 4, e0 = el * 4;
  const int ebase = tile * 16;

  float* B1 = &lds[wid * 2 * F * SE];
  float* B2 = B1 + F * SE;

  // ---- stage node_s[src] -> B1, node_s[dst] -> B2, TRANSPOSED [k][e] ----
  #pragma unroll 4
  for (int le = 0; le < 16; ++le) {
    int e = ebase + le; if (e >= E) e = E - 1;
    B1[lane * SE + le] = node_s[(size_t)src[e] * F + lane];
    B2[lane * SE + le] = node_s[(size_t)dst[e] * F + lane];
  }
  __builtin_amdgcn_wave_barrier();

  // nn = [src|dst] @ W_nn
  float accN[4][4] = {};
  gemm64(B1, W_nn,          f0, e0, accN);
  gemm64(B2, W_nn + 64 * F, f0, e0, accN);
  __builtin_amdgcn_wave_barrier();

  // ---- stage edge_s -> B1 (overwrite src staging) ----
  #pragma unroll 4
  for (int le = 0; le < 16; ++le) {
    int e = ebase + le; if (e >= E) e = E - 1;
    B1[lane * SE + le] = edge_s[(size_t)e * F + lane];
  }
  __builtin_amdgcn_wave_barrier();

  // lane's own 4x4 edge_s tile for the residual, kept in registers
  float esr[4][4];
  #pragma unroll
  for (int j = 0; j < 4; ++j) {
    float t[4]; ld4(B1 + (f0 + j) * SE + e0, t);
    esr[0][j] = t[0]; esr[1][j] = t[1]; esr[2][j] = t[2]; esr[3][j] = t[3];
  }

  // ep = edge_s @ W_ep
  float accP[4][4] = {};
  gemm64(B1, W_ep, f0, e0, accP);
  float bnn[4]; ld4(b_nn + f0, bnn);
  float bep[4]; ld4(b_ep + f0, bep);

  // em = nn * ep -> B2 transposed
  #pragma unroll
  for (int j = 0; j < 4; ++j) {
    float4 v;
    v.x = (accN[0][j] + bnn[j]) * (accP[0][j] + bep[j]);
    v.y = (accN[1][j] + bnn[j]) * (accP[1][j] + bep[j]);
    v.z = (accN[2][j] + bnn[j]) * (accP[2][j] + bep[j]);
    v.w = (accN[3][j] + bnn[j]) * (accP[3][j] + bep[j]);
    *(float4*)(B2 + (f0 + j) * SE + e0) = v;
  }
  __builtin_amdgcn_wave_barrier();

  // h = silu(em @ W_g1 + b_g1) -> B1 transposed
  float accH[4][4] = {};
  gemm64(B2, W_g1, f0, e0, accH);
  float bg1[4]; ld4(b_g1 + f0, bg1);
  #pragma unroll
  for (int j = 0; j < 4; ++j) {
    float4 v;
    v.x = silu_f(accH[0][j] + bg1[j]);
    v.y = silu_f(accH[1][j] + bg1[j]);
    v.z = silu_f(accH[2][j] + bg1[j]);
    v.w = silu_f(accH[3][j] + bg1[j]);
    *(float4*)(B1 + (f0 + j) * SE + e0) = v;
  }
  __builtin_amdgcn_wave_barrier();

  // es_upd = (h @ W_g2 + b_g2) * c
  float accS[4][4] = {};
  gemm64(B1, W_g2, f0, e0, accS);
  float bg2[4]; ld4(b_g2 + f0, bg2);
  float cc[4];
  #pragma unroll
  for (int i = 0; i < 4; ++i) {
    int e = ebase + e0 + i; if (e >= E) e = E - 1;
    float d = dist[e];
    cc[i] = (d < 5.0f) ? 0.5f * (cosf(3.14159265358979f * d * 0.2f) + 1.0f) : 0.0f;
  }
  #pragma unroll
  for (int i = 0; i < 4; ++i)
    #pragma unroll
    for (int j = 0; j < 4; ++j)
      accS[i][j] = (accS[i][j] + bg2[j]) * cc[i];

  // edge_s_out = es_upd + edge_s (residual from regs)
  #pragma unroll
  for (int i = 0; i < 4; ++i) {
    int e = ebase + e0 + i;
    if (e < E) {
      float4 o;
      o.x = accS[i][0] + esr[i][0];
      o.y = accS[i][1] + esr[i][1];
      o.z = accS[i][2] + esr[i][2];
      o.w = accS[i][3] + esr[i][3];
      *(float4*)(es_out + (size_t)e * F + f0) = o;
    }
  }

  // es_upd -> B2 transposed for the W_ev GEMM
  #pragma unroll
  for (int j = 0; j < 4; ++j) {
    float4 v;
    v.x = accS[0][j]; v.y = accS[1][j]; v.z = accS[2][j]; v.w = accS[3][j];
    *(float4*)(B2 + (f0 + j) * SE + e0) = v;
  }
  __builtin_amdgcn_wave_barrier();

  // vch = es_upd @ W_ev + b_ev  (nch, ech, rch)
  float vc[3][4][4] = {};
  #pragma unroll 2
  for (int k = 0; k < F; ++k) {
    float a[4]; ld4(B2 + k * SE + e0, a);
    float w0[4], w1[4], w2[4];
    ld4(W_ev + k * 192 + f0, w0);
    ld4(W_ev + k * 192 + 64 + f0, w1);
    ld4(W_ev + k * 192 + 128 + f0, w2);
    #pragma unroll
    for (int i = 0; i < 4; ++i)
      #pragma unroll
      for (int j = 0; j < 4; ++j) {
        vc[0][i][j] = fmaf(a[i], w0[j], vc[0][i][j]);
        vc[1][i][j] = fmaf(a[i], w1[j], vc[1][i][j]);
        vc[2][i][j] = fmaf(a[i], w2[j], vc[2][i][j]);
      }
  }
  {
    float be0[4], be1[4], be2[4];
    ld4(b_ev + f0, be0); ld4(b_ev + 64 + f0, be1); ld4(b_ev + 128 + f0, be2);
    #pragma unroll
    for (int i = 0; i < 4; ++i)
      #pragma unroll
      for (int j = 0; j < 4; ++j) {
        vc[0][i][j] += be0[j]; vc[1][i][j] += be1[j]; vc[2][i][j] += be2[j];
      }
  }

  // ev_upd = (node_v[src]*nch + edge_v*ech + vctr*rch) * c ; edge_v_out = ev_upd + edge_v
  #pragma unroll
  for (int i = 0; i < 4; ++i) {
    int e = ebase + e0 + i;
    if (e >= E) continue;
    int s = src[e];
    #pragma unroll
    for (int dd = 0; dd < 3; ++dd) {
      float nv[4]; ld4(node_v + (size_t)s * 192 + dd * 64 + f0, nv);
      float ev[4]; ld4(edge_v + (size_t)e * 192 + dd * 64 + f0, ev);
      float vn = vctr[e * 3 + dd];
      float4 o;
      #pragma unroll
      for (int j = 0; j < 4; ++j) {
        float evu = (nv[j] * vc[0][i][j] + ev[j] * vc[1][i][j] + vn * vc[2][i][j]) * cc[i];
        ((float*)&o)[j] = evu + ev[j];
      }
      *(float4*)(ev_out + (size_t)e * 192 + dd * 64 + f0) = o;
    }
  }
}

// ============ node kernel: CSR gather + node update ============
__global__ __launch_bounds__(256) void node_kernel(
    const float* __restrict__ node_s, const float* __restrict__ node_v,
    const float* __restrict__ edge_s, const float* __restrict__ edge_v,
    const float* __restrict__ es_r,   const float* __restrict__ ev_r,
    const int* __restrict__ rowstart, const int* __restrict__ elist,
    const float* __restrict__ W_nvout,
    const float* __restrict__ W_nvc, const float* __restrict__ b_nvc,
    const float* __restrict__ W_nvp,
    const float* __restrict__ W_nsp, const float* __restrict__ b_nsp,
    const float* __restrict__ ln_g, const float* __restrict__ ln_b,
    const float* __restrict__ cn_s,
    float* __restrict__ ns_out, float* __restrict__ nv_out, int N)
{
  __shared__ __align__(16) float scm[4 * 8 * 68];
  const int wid = threadIdx.x >> 6, lane = threadIdx.x & 63;
  const int n = blockIdx.x * 4 + wid;
  if (n >= N) return;
  float* S = &scm[wid * 8 * 68];

  // ---- gather scatter-mean from incident edges (raw = out - residual input) ----
  const int rs = rowstart[n], re = rowstart[n + 1];
  float nes = 0.0f, nev0 = 0.0f, nev1 = 0.0f, nev2 = 0.0f;
  for (int idx = rs; idx < re; ++idx) {
    int e = elist[idx];
    size_t b64 = (size_t)e * 64, b192 = (size_t)e * 192;
    nes  += es_r[b64 + lane]        - edge_s[b64 + lane];
    nev0 += ev_r[b192 + lane]       - edge_v[b192 + lane];
    nev1 += ev_r[b192 + 64 + lane]  - edge_v[b192 + 64 + lane];
    nev2 += ev_r[b192 + 128 + lane] - edge_v[b192 + 128 + lane];
  }
  const float inv = 1.0f / fmaxf((float)(re - rs), 1.0f);
  nes *= inv; nev0 *= inv; nev1 *= inv; nev2 *= inv;

  S[0 * 68 + lane] = nev0; S[1 * 68 + lane] = nev1;
  S[2 * 68 + lane] = nev2; S[3 * 68 + lane] = nes;
  __builtin_amdgcn_wave_barrier();

  // n_ev @ W_nvout -> o1,o2,o3
  float o1[3] = {}, o2[3] = {}, o3[3] = {};
  for (int k = 0; k < 64; k += 4) {
    float a0[4], a1[4], a2[4];
    ld4(S + 0 * 68 + k, a0); ld4(S + 1 * 68 + k, a1); ld4(S + 2 * 68 + k, a2);
    #pragma unroll
    for (int kk = 0; kk < 4; ++kk) {
      float w0 = W_nvout[(k + kk) * 192 + lane];
      float w1 = W_nvout[(k + kk) * 192 + 64 + lane];
      float w2 = W_nvout[(k + kk) * 192 + 128 + lane];
      o1[0] = fmaf(a0[kk], w0, o1[0]); o1[1] = fmaf(a1[kk], w0, o1[1]); o1[2] = fmaf(a2[kk], w0, o1[2]);
      o2[0] = fmaf(a0[kk], w1, o2[0]); o2[1] = fmaf(a1[kk], w1, o2[1]); o2[2] = fmaf(a2[kk], w1, o2[2]);
      o3[0] = fmaf(a0[kk], w2, o3[0]); o3[1] = fmaf(a1[kk], w2, o3[1]); o3[2] = fmaf(a2[kk], w2, o3[2]);
    }
  }
  float nrm = sqrtf(o3[0] * o3[0] + o3[1] * o3[1] + o3[2] * o3[2]);
  S[4 * 68 + lane] = nrm;
  __builtin_amdgcn_wave_barrier();

  // v_channel = [n_es | ||o3||] @ W_nvc + b_nvc
  float vch = 0.0f;
  for (int k = 0; k < 64; k += 4) {
    float a[4], b[4];
    ld4(S + 3 * 68 + k, a); ld4(S + 4 * 68 + k, b);
    #pragma unroll
    for (int kk = 0; kk < 4; ++kk) {
      vch = fmaf(a[kk], W_nvc[(k + kk) * 64 + lane], vch);
      vch = fmaf(b[kk], W_nvc[(64 + k + kk) * 64 + lane], vch);
    }
  }
  vch += b_nvc[lane];

  float nvu[3];
  #pragma unroll
  for (int dd = 0; dd < 3; ++dd) {
    nvu[dd] = o1[dd] * vch + o2[dd];
    S[(5 + dd) * 68 + lane] = nvu[dd];
  }
  __builtin_amdgcn_wave_barrier();

  // nvp1/nvp2 = nv_upd @ W_nvp (split)
  float p1[3] = {}, p2[3] = {};
  for (int k = 0; k < 64; k += 4) {
    float a0[4], a1[4], a2[4];
    ld4(S + 5 * 68 + k, a0); ld4(S + 6 * 68 + k, a1); ld4(S + 7 * 68 + k, a2);
    #pragma unroll
    for (int kk = 0; kk < 4; ++kk) {
      float w1 = W_nvp[(k + kk) * 128 + lane];
      float w2 = W_nvp[(k + kk) * 128 + 64 + lane];
      p1[0] = fmaf(a0[kk], w1, p1[0]); p1[1] = fmaf(a1[kk], w1, p1[1]); p1[2] = fmaf(a2[kk], w1, p1[2]);
      p2[0] = fmaf(a0[kk], w2, p2[0]); p2[1] = fmaf(a1[kk], w2, p2[1]); p2[2] = fmaf(a2[kk], w2, p2[2]);
    }
  }

  // ns1/ns2 = silu(n_es @ W_nsp + b_nsp) split
  float s1a = 0.0f, s2a = 0.0f;
  for (int k = 0; k < 64; k += 4) {
    float a[4];
    ld4(S + 3 * 68 + k, a);
    #pragma unroll
    for (int kk = 0; kk < 4; ++kk) {
      s1a = fmaf(a[kk], W_nsp[(k + kk) * 128 + lane], s1a);
      s2a = fmaf(a[kk], W_nsp[(k + kk) * 128 + 64 + lane], s2a);
    }
  }
  float s1 = silu_f(s1a + b_nsp[lane]);
  float s2 = silu_f(s2a + b_nsp[64 + lane]);

  float nvdot = p1[0] * p2[0] + p1[1] * p2[1] + p1[2] * p2[2];
  float nsu = nvdot * s1 + s2;

  // LayerNorm over 64 features (wave-wide)
  float xs = nsu + node_s[n * 64 + lane];
  float sum = xs, sumsq = xs * xs;
  #pragma unroll
  for (int o = 32; o; o >>= 1) {
    sum += __shfl_xor(sum, o);
    sumsq += __shfl_xor(sumsq, o);
  }
  float mu = sum * (1.0f / 64.0f);
  float var = sumsq * (1.0f / 64.0f) - mu * mu;
  ns_out[n * 64 + lane] = (xs - mu) * rsqrtf(var + 1e-5f) * ln_g[lane] + ln_b[lane];

  // CoorsNorm over 3D axis (lane-local)
  float vv[3];
  #pragma unroll
  for (int dd = 0; dd < 3; ++dd) vv[dd] = nvu[dd] + node_v[n * 192 + dd * 64 + lane];
  float vn2 = sqrtf(vv[0] * vv[0] + vv[1] * vv[1] + vv[2] * vv[2]);
  float scale = cn_s[lane] / fmaxf(vn2, 1e-8f);
  #pragma unroll
  for (int dd = 0; dd < 3; ++dd)
    nv_out[n * 192 + dd * 64 + lane] = vv[dd] * scale;
}

extern "C" void kernel_launch(void* const* d_in, const int* in_sizes, int n_in,
                              void* d_out, int out_size, void* d_ws, size_t ws_size,
                              hipStream_t stream) {
  const float* node_s = (const float*)d_in[0];
  const float* node_v = (const float*)d_in[1];
  const float* edge_s = (const float*)d_in[2];
  const float* edge_v = (const float*)d_in[3];
  const float* dist   = (const float*)d_in[4];
  const float* vctr   = (const float*)d_in[5];
  const int*   src    = (const int*)d_in[6];
  const int*   dst    = (const int*)d_in[7];
  const float* W_nn = (const float*)d_in[8];  const float* b_nn = (const float*)d_in[9];
  const float* W_ep = (const float*)d_in[10]; const float* b_ep = (const float*)d_in[11];
  const float* W_g1 = (const float*)d_in[12]; const float* b_g1 = (const float*)d_in[13];
  const float* W_g2 = (const float*)d_in[14]; const float* b_g2 = (const float*)d_in[15];
  const float* W_ev = (const float*)d_in[16]; const float* b_ev = (const float*)d_in[17];
  const float* W_nvout = (const float*)d_in[18];
  const float* W_nvc = (const float*)d_in[19]; const float* b_nvc = (const float*)d_in[20];
  const float* W_nvp = (const float*)d_in[21];
  const float* W_nsp = (const float*)d_in[22]; const float* b_nsp = (const float*)d_in[23];
  const float* ln_g = (const float*)d_in[24]; const float* ln_b = (const float*)d_in[25];
  const float* cn_s = (const float*)d_in[26];

  const int N = in_sizes[0] / 64;
  const int E = in_sizes[2] / 64;

  float* out    = (float*)d_out;
  float* ns_out = out;
  float* nv_out = out + (size_t)N * 64;
  float* es_out = out + (size_t)N * 256;
  float* ev_out = out + (size_t)N * 256 + (size_t)E * 64;

  // ws: CSR arrays (ints)
  int* cnt      = (int*)d_ws;          // N (histogram, then scatter cursor)
  int* rowstart = cnt + N;             // N+1
  int* elist    = rowstart + N + 1;    // E

  hipMemsetAsync(cnt, 0, (size_t)N * sizeof(int), stream);
  hist_kernel<<<(E + 255) / 256, 256, 0, stream>>>(dst, cnt, E);
  scan_kernel<<<1, 1024, 0, stream>>>(cnt, rowstart, N);
  scatter_kernel<<<(E + 255) / 256, 256, 0, stream>>>(dst, cnt, elist, E);

  int n_tiles = (E + 15) / 16;
  edge_kernel<<<(n_tiles + 3) / 4, 256, 0, stream>>>(
      node_s, node_v, edge_s, edge_v, dist, vctr, src, dst,
      W_nn, b_nn, W_ep, b_ep, W_g1, b_g1, W_g2, b_g2, W_ev, b_ev,
      es_out, ev_out, E, n_tiles);

  node_kernel<<<(N + 3) / 4, 256, 0, stream>>>(
      node_s, node_v, edge_s, edge_v, es_out, ev_out, rowstart, elist,
      W_nvout, W_nvc, b_nvc, W_nvp, W_nsp, b_nsp,
      ln_g, ln_b, cn_s, ns_out, nv_out, N);
}

// Round 3
// 1095.923 us; speedup vs baseline: 1.9685x; 1.1284x over previous
//
#include <hip/hip_runtime.h>
#include <hip/hip_bf16.h>
#include <math.h>

typedef __attribute__((ext_vector_type(8))) short bf16x8;
typedef __attribute__((ext_vector_type(4))) float f32x4;

#define MFMA16(a, b, c) __builtin_amdgcn_mfma_f32_16x16x32_bf16((a), (b), (c), 0, 0, 0)

__device__ __forceinline__ float silu_f(float x) { return x / (1.0f + expf(-x)); }

__device__ __forceinline__ unsigned short f2bf(float f) {
  union { __hip_bfloat16 h; unsigned short u; } c;
  c.h = __float2bfloat16(f);
  return c.u;
}
__device__ __forceinline__ unsigned pk2(float a, float b) {
  return (unsigned)f2bf(a) | ((unsigned)f2bf(b) << 16);
}

// activation fragment (B-operand): lane holds col m=lane&15, k = ks*32 + (lane>>4)*8 ..+7
// LDS layout row-major [row][K] bf16, XOR-swizzled: byte ^= (row&7)<<4
__device__ __forceinline__ bf16x8 ld_act(const unsigned short* buf, int strideB, int ks, int lane) {
  int row = lane & 15;
  int off = row * strideB + ks * 64 + ((lane >> 4) << 4);
  off ^= (row & 7) << 4;
  return *(const bf16x8*)((const char*)buf + off);
}

// weight fragment (A-operand): lane holds row n=rowbase+(lane&15), k contiguous; Wt row-major [n][K] bf16 in global
__device__ __forceinline__ bf16x8 ld_w(const unsigned short* Wt, int rowbase, int strideB, int ks, int lane) {
  return *(const bf16x8*)((const char*)Wt + (size_t)(rowbase + (lane & 15)) * strideB + ks * 64 + ((lane >> 4) << 4));
}

// ============ weight prep: Wt[n][k] = bf16(W[k][n]) ============
__global__ void wprep_kernel(const float* __restrict__ W, unsigned short* __restrict__ Wt,
                             int K, int Nn) {
  int idx = blockIdx.x * 256 + threadIdx.x;
  if (idx < K * Nn) {
    int n = idx / K, k = idx - n * K;
    Wt[idx] = f2bf(W[(size_t)k * Nn + n]);
  }
}

// ============ CSR build ============
__global__ void hist_kernel(const int* __restrict__ dst, int* __restrict__ cnt, int E) {
  int i = blockIdx.x * blockDim.x + threadIdx.x;
  if (i < E) atomicAdd(&cnt[dst[i]], 1);
}

__global__ __launch_bounds__(1024) void scan_kernel(int* __restrict__ cnt,
                                                    int* __restrict__ rowstart, int N) {
  __shared__ int wsum[16];
  const int tid = threadIdx.x;
  const int wv = tid >> 6;
  int carry = 0;
  for (int base = 0; base < N; base += 1024) {
    int i = base + tid;
    int v = (i < N) ? cnt[i] : 0;
    int x = v;
    #pragma unroll
    for (int o = 1; o < 64; o <<= 1) {
      int y = __shfl_up(x, o);
      if ((tid & 63) >= o) x += y;
    }
    if ((tid & 63) == 63) wsum[wv] = x;
    __syncthreads();
    if (tid < 16) {
      int s = wsum[tid];
      #pragma unroll
      for (int o = 1; o < 16; o <<= 1) {
        int y = __shfl_up(s, o);
        if (tid >= o) s += y;
      }
      wsum[tid] = s;
    }
    __syncthreads();
    int woff = (wv > 0) ? wsum[wv - 1] : 0;
    if (i < N) {
      int excl = carry + woff + x - v;
      rowstart[i] = excl;
      cnt[i] = excl;          // cnt becomes the scatter cursor
    }
    carry += wsum[15];
    __syncthreads();
  }
  if (tid == 0) rowstart[N] = carry;
}

__global__ void scatter_kernel(const int* __restrict__ dst, int* __restrict__ cursor,
                               int* __restrict__ elist, int E) {
  int i = blockIdx.x * blockDim.x + threadIdx.x;
  if (i < E) {
    int pos = atomicAdd(&cursor[dst[i]], 1);
    elist[pos] = i;
  }
}

// ============ edge kernel: bf16 MFMA chain ============
// Per wave: 16 edges. All GEMMs computed as D = W^T x Act^T via mfma(weightFrag, actFrag, acc):
// C/D: col = lane&15 = edge m, row = (lane>>4)*4+q = feature n (4 consecutive feats per lane).
__global__ __launch_bounds__(256) void edge_kernel(
    const float* __restrict__ node_s, const float* __restrict__ node_v,
    const float* __restrict__ edge_s, const float* __restrict__ edge_v,
    const float* __restrict__ dist,   const float* __restrict__ vctr,
    const int* __restrict__ src,      const int* __restrict__ dst,
    const unsigned short* __restrict__ wnn_t, const float* __restrict__ b_nn,
    const unsigned short* __restrict__ wep_t, const float* __restrict__ b_ep,
    const unsigned short* __restrict__ wg1_t, const float* __restrict__ b_g1,
    const unsigned short* __restrict__ wg2_t, const float* __restrict__ b_g2,
    const unsigned short* __restrict__ wev_t, const float* __restrict__ b_ev,
    float* __restrict__ es_out, float* __restrict__ ev_out,
    int E, int n_tiles)
{
  // per wave: bufA [16][128] bf16 (4KB) for [src|dst] feats, bufB [16][64] bf16 (2KB)
  __shared__ __align__(16) unsigned short lds[4 * 3072]; // 24KB/block
  const int wid  = threadIdx.x >> 6;
  const int lane = threadIdx.x & 63;
  const int tile = blockIdx.x * 4 + wid;
  if (tile >= n_tiles) return;
  const int ebase = tile * 16;
  unsigned short* bufA = lds + wid * 3072;
  unsigned short* bufB = bufA + 2048;

  const int m  = lane & 15;   // edge within tile (compute phase)
  const int nb = lane >> 4;   // feature sub-block (n = nt*16 + nb*4 + q)

  // ---- stage node_s[src]->bufA[:,0:64], node_s[dst]->bufA[:,64:128], edge_s->bufB (bf16, swizzled) ----
  {
    const int sm = lane >> 5;      // which edge of the pair
    const int kk = lane & 31;      // float-pair index
    #pragma unroll
    for (int p = 0; p < 8; ++p) {
      int le = p * 2 + sm;
      int e = ebase + le; if (e >= E) e = E - 1;
      int s = src[e], d = dst[e];
      float2 vs = *(const float2*)(node_s + (size_t)s * 64 + 2 * kk);
      float2 vd = *(const float2*)(node_s + (size_t)d * 64 + 2 * kk);
      float2 ve = *(const float2*)(edge_s + (size_t)e * 64 + 2 * kk);
      unsigned swz = (le & 7) << 4;
      *(unsigned*)((char*)bufA + ((le * 256 + kk * 4) ^ swz))       = pk2(vs.x, vs.y);
      *(unsigned*)((char*)bufA + ((le * 256 + 128 + kk * 4) ^ swz)) = pk2(vd.x, vd.y);
      *(unsigned*)((char*)bufB + ((le * 128 + kk * 4) ^ swz))       = pk2(ve.x, ve.y);
    }
  }
  __builtin_amdgcn_wave_barrier();

  const f32x4 z4 = {0.0f, 0.0f, 0.0f, 0.0f};

  // ---- nn = [src|dst] @ W_nn  (K=128) ----
  bf16x8 a0 = ld_act(bufA, 256, 0, lane), a1 = ld_act(bufA, 256, 1, lane);
  bf16x8 a2 = ld_act(bufA, 256, 2, lane), a3 = ld_act(bufA, 256, 3, lane);
  f32x4 accN[4] = {z4, z4, z4, z4};
  #pragma unroll
  for (int nt = 0; nt < 4; ++nt) {
    accN[nt] = MFMA16(ld_w(wnn_t, nt * 16, 256, 0, lane), a0, accN[nt]);
    accN[nt] = MFMA16(ld_w(wnn_t, nt * 16, 256, 1, lane), a1, accN[nt]);
    accN[nt] = MFMA16(ld_w(wnn_t, nt * 16, 256, 2, lane), a2, accN[nt]);
    accN[nt] = MFMA16(ld_w(wnn_t, nt * 16, 256, 3, lane), a3, accN[nt]);
  }

  // ---- ep = edge_s @ W_ep (K=64) ----
  bf16x8 b0 = ld_act(bufB, 128, 0, lane), b1 = ld_act(bufB, 128, 1, lane);
  f32x4 accP[4] = {z4, z4, z4, z4};
  #pragma unroll
  for (int nt = 0; nt < 4; ++nt) {
    accP[nt] = MFMA16(ld_w(wep_t, nt * 16, 128, 0, lane), b0, accP[nt]);
    accP[nt] = MFMA16(ld_w(wep_t, nt * 16, 128, 1, lane), b1, accP[nt]);
  }

  // ---- em = (nn+b_nn)*(ep+b_ep) -> bufB (bf16) ----
  const unsigned swzm = (m & 7) << 4;
  #pragma unroll
  for (int nt = 0; nt < 4; ++nt) {
    f32x4 bn = *(const f32x4*)(b_nn + nt * 16 + nb * 4);
    f32x4 bp = *(const f32x4*)(b_ep + nt * 16 + nb * 4);
    float e0 = (accN[nt].x + bn.x) * (accP[nt].x + bp.x);
    float e1 = (accN[nt].y + bn.y) * (accP[nt].y + bp.y);
    float e2 = (accN[nt].z + bn.z) * (accP[nt].z + bp.z);
    float e3 = (accN[nt].w + bn.w) * (accP[nt].w + bp.w);
    uint2 w2; w2.x = pk2(e0, e1); w2.y = pk2(e2, e3);
    *(uint2*)((char*)bufB + ((m * 128 + nt * 32 + nb * 8) ^ swzm)) = w2;
  }
  __builtin_amdgcn_wave_barrier();

  // ---- h = silu(em @ W_g1 + b_g1) -> bufB ----
  bf16x8 c0 = ld_act(bufB, 128, 0, lane), c1 = ld_act(bufB, 128, 1, lane);
  f32x4 accH[4] = {z4, z4, z4, z4};
  #pragma unroll
  for (int nt = 0; nt < 4; ++nt) {
    accH[nt] = MFMA16(ld_w(wg1_t, nt * 16, 128, 0, lane), c0, accH[nt]);
    accH[nt] = MFMA16(ld_w(wg1_t, nt * 16, 128, 1, lane), c1, accH[nt]);
  }
  #pragma unroll
  for (int nt = 0; nt < 4; ++nt) {
    f32x4 bg = *(const f32x4*)(b_g1 + nt * 16 + nb * 4);
    float h0 = silu_f(accH[nt].x + bg.x);
    float h1 = silu_f(accH[nt].y + bg.y);
    float h2 = silu_f(accH[nt].z + bg.z);
    float h3 = silu_f(accH[nt].w + bg.w);
    uint2 w2; w2.x = pk2(h0, h1); w2.y = pk2(h2, h3);
    *(uint2*)((char*)bufB + ((m * 128 + nt * 32 + nb * 8) ^ swzm)) = w2;
  }
  __builtin_amdgcn_wave_barrier();

  // ---- es_upd = (h @ W_g2 + b_g2) * c ----
  bf16x8 d0 = ld_act(bufB, 128, 0, lane), d1 = ld_act(bufB, 128, 1, lane);
  f32x4 accS[4] = {z4, z4, z4, z4};
  #pragma unroll
  for (int nt = 0; nt < 4; ++nt) {
    accS[nt] = MFMA16(ld_w(wg2_t, nt * 16, 128, 0, lane), d0, accS[nt]);
    accS[nt] = MFMA16(ld_w(wg2_t, nt * 16, 128, 1, lane), d1, accS[nt]);
  }
  const int e = ebase + m;
  float dd_ = dist[e];
  const float cc = (dd_ < 5.0f) ? 0.5f * (cosf(3.14159265358979f * dd_ * 0.2f) + 1.0f) : 0.0f;
  #pragma unroll
  for (int nt = 0; nt < 4; ++nt) {
    f32x4 bg = *(const f32x4*)(b_g2 + nt * 16 + nb * 4);
    accS[nt].x = (accS[nt].x + bg.x) * cc;
    accS[nt].y = (accS[nt].y + bg.y) * cc;
    accS[nt].z = (accS[nt].z + bg.z) * cc;
    accS[nt].w = (accS[nt].w + bg.w) * cc;
  }

  // edge_s_out = es_upd + edge_s (fp32 residual from global, L2-hot)
  {
    const float* esrow = edge_s + (size_t)e * 64;
    float* eorow = es_out + (size_t)e * 64;
    #pragma unroll
    for (int nt = 0; nt < 4; ++nt) {
      float4 r = *(const float4*)(esrow + nt * 16 + nb * 4);
      float4 o;
      o.x = accS[nt].x + r.x; o.y = accS[nt].y + r.y;
      o.z = accS[nt].z + r.z; o.w = accS[nt].w + r.w;
      *(float4*)(eorow + nt * 16 + nb * 4) = o;
    }
  }

  // es_upd -> bufB (bf16) for the W_ev GEMM
  #pragma unroll
  for (int nt = 0; nt < 4; ++nt) {
    uint2 w2;
    w2.x = pk2(accS[nt].x, accS[nt].y);
    w2.y = pk2(accS[nt].z, accS[nt].w);
    *(uint2*)((char*)bufB + ((m * 128 + nt * 32 + nb * 8) ^ swzm)) = w2;
  }
  __builtin_amdgcn_wave_barrier();

  // ---- vch = es_upd @ W_ev + b_ev : 12 n-tiles (nch 0-3, ech 4-7, rch 8-11) ----
  bf16x8 g0 = ld_act(bufB, 128, 0, lane), g1f = ld_act(bufB, 128, 1, lane);
  f32x4 accV[12];
  #pragma unroll
  for (int i = 0; i < 12; ++i) accV[i] = z4;
  #pragma unroll
  for (int ch = 0; ch < 3; ++ch)
    #pragma unroll
    for (int nt = 0; nt < 4; ++nt) {
      accV[ch * 4 + nt] = MFMA16(ld_w(wev_t, ch * 64 + nt * 16, 128, 0, lane), g0,  accV[ch * 4 + nt]);
      accV[ch * 4 + nt] = MFMA16(ld_w(wev_t, ch * 64 + nt * 16, 128, 1, lane), g1f, accV[ch * 4 + nt]);
    }
  #pragma unroll
  for (int ch = 0; ch < 3; ++ch)
    #pragma unroll
    for (int nt = 0; nt < 4; ++nt) {
      f32x4 bv = *(const f32x4*)(b_ev + ch * 64 + nt * 16 + nb * 4);
      accV[ch * 4 + nt].x += bv.x; accV[ch * 4 + nt].y += bv.y;
      accV[ch * 4 + nt].z += bv.z; accV[ch * 4 + nt].w += bv.w;
    }

  // ---- ev_upd = (node_v[src]*nch + edge_v*ech + vctr*rch)*c ; ev_out = ev_upd + edge_v ----
  {
    const int s = src[e];
    const float* nvb = node_v + (size_t)s * 192;
    const float* evb = edge_v + (size_t)e * 192;
    float* eob = ev_out + (size_t)e * 192;
    #pragma unroll
    for (int dd = 0; dd < 3; ++dd) {
      const float vn = vctr[e * 3 + dd];
      #pragma unroll
      for (int nt = 0; nt < 4; ++nt) {
        const int n0 = nt * 16 + nb * 4;
        float4 nv = *(const float4*)(nvb + dd * 64 + n0);
        float4 ev = *(const float4*)(evb + dd * 64 + n0);
        float4 o;
        o.x = (nv.x * accV[nt].x + ev.x * accV[4 + nt].x + vn * accV[8 + nt].x) * cc + ev.x;
        o.y = (nv.y * accV[nt].y + ev.y * accV[4 + nt].y + vn * accV[8 + nt].y) * cc + ev.y;
        o.z = (nv.z * accV[nt].z + ev.z * accV[4 + nt].z + vn * accV[8 + nt].z) * cc + ev.z;
        o.w = (nv.w * accV[nt].w + ev.w * accV[4 + nt].w + vn * accV[8 + nt].w) * cc + ev.w;
        *(float4*)(eob + dd * 64 + n0) = o;
      }
    }
  }
}

// ============ node kernel: CSR gather + node update (fp32) ============
__device__ __forceinline__ void ld4(const float* p, float o[4]) {
  float4 v = *(const float4*)p;
  o[0] = v.x; o[1] = v.y; o[2] = v.z; o[3] = v.w;
}

__global__ __launch_bounds__(256) void node_kernel(
    const float* __restrict__ node_s, const float* __restrict__ node_v,
    const float* __restrict__ edge_s, const float* __restrict__ edge_v,
    const float* __restrict__ es_r,   const float* __restrict__ ev_r,
    const int* __restrict__ rowstart, const int* __restrict__ elist,
    const float* __restrict__ W_nvout,
    const float* __restrict__ W_nvc, const float* __restrict__ b_nvc,
    const float* __restrict__ W_nvp,
    const float* __restrict__ W_nsp, const float* __restrict__ b_nsp,
    const float* __restrict__ ln_g, const float* __restrict__ ln_b,
    const float* __restrict__ cn_s,
    float* __restrict__ ns_out, float* __restrict__ nv_out, int N)
{
  __shared__ __align__(16) float scm[4 * 8 * 68];
  const int wid = threadIdx.x >> 6, lane = threadIdx.x & 63;
  const int n = blockIdx.x * 4 + wid;
  if (n >= N) return;
  float* S = &scm[wid * 8 * 68];

  // ---- gather scatter-mean from incident edges (raw = out - residual input) ----
  const int rs = rowstart[n], re = rowstart[n + 1];
  float nes = 0.0f, nev0 = 0.0f, nev1 = 0.0f, nev2 = 0.0f;
  for (int idx = rs; idx < re; ++idx) {
    int e = elist[idx];
    size_t b64 = (size_t)e * 64, b192 = (size_t)e * 192;
    nes  += es_r[b64 + lane]        - edge_s[b64 + lane];
    nev0 += ev_r[b192 + lane]       - edge_v[b192 + lane];
    nev1 += ev_r[b192 + 64 + lane]  - edge_v[b192 + 64 + lane];
    nev2 += ev_r[b192 + 128 + lane] - edge_v[b192 + 128 + lane];
  }
  const float inv = 1.0f / fmaxf((float)(re - rs), 1.0f);
  nes *= inv; nev0 *= inv; nev1 *= inv; nev2 *= inv;

  S[0 * 68 + lane] = nev0; S[1 * 68 + lane] = nev1;
  S[2 * 68 + lane] = nev2; S[3 * 68 + lane] = nes;
  __builtin_amdgcn_wave_barrier();

  // n_ev @ W_nvout -> o1,o2,o3
  float o1[3] = {}, o2[3] = {}, o3[3] = {};
  for (int k = 0; k < 64; k += 4) {
    float a0[4], a1[4], a2[4];
    ld4(S + 0 * 68 + k, a0); ld4(S + 1 * 68 + k, a1); ld4(S + 2 * 68 + k, a2);
    #pragma unroll
    for (int kk = 0; kk < 4; ++kk) {
      float w0 = W_nvout[(k + kk) * 192 + lane];
      float w1 = W_nvout[(k + kk) * 192 + 64 + lane];
      float w2 = W_nvout[(k + kk) * 192 + 128 + lane];
      o1[0] = fmaf(a0[kk], w0, o1[0]); o1[1] = fmaf(a1[kk], w0, o1[1]); o1[2] = fmaf(a2[kk], w0, o1[2]);
      o2[0] = fmaf(a0[kk], w1, o2[0]); o2[1] = fmaf(a1[kk], w1, o2[1]); o2[2] = fmaf(a2[kk], w1, o2[2]);
      o3[0] = fmaf(a0[kk], w2, o3[0]); o3[1] = fmaf(a1[kk], w2, o3[1]); o3[2] = fmaf(a2[kk], w2, o3[2]);
    }
  }
  float nrm = sqrtf(o3[0] * o3[0] + o3[1] * o3[1] + o3[2] * o3[2]);
  S[4 * 68 + lane] = nrm;
  __builtin_amdgcn_wave_barrier();

  // v_channel = [n_es | ||o3||] @ W_nvc + b_nvc
  float vch = 0.0f;
  for (int k = 0; k < 64; k += 4) {
    float a[4], b[4];
    ld4(S + 3 * 68 + k, a); ld4(S + 4 * 68 + k, b);
    #pragma unroll
    for (int kk = 0; kk < 4; ++kk) {
      vch = fmaf(a[kk], W_nvc[(k + kk) * 64 + lane], vch);
      vch = fmaf(b[kk], W_nvc[(64 + k + kk) * 64 + lane], vch);
    }
  }
  vch += b_nvc[lane];

  float nvu[3];
  #pragma unroll
  for (int dd = 0; dd < 3; ++dd) {
    nvu[dd] = o1[dd] * vch + o2[dd];
    S[(5 + dd) * 68 + lane] = nvu[dd];
  }
  __builtin_amdgcn_wave_barrier();

  // nvp1/nvp2 = nv_upd @ W_nvp (split)
  float p1[3] = {}, p2[3] = {};
  for (int k = 0; k < 64; k += 4) {
    float a0[4], a1[4], a2[4];
    ld4(S + 5 * 68 + k, a0); ld4(S + 6 * 68 + k, a1); ld4(S + 7 * 68 + k, a2);
    #pragma unroll
    for (int kk = 0; kk < 4; ++kk) {
      float w1 = W_nvp[(k + kk) * 128 + lane];
      float w2 = W_nvp[(k + kk) * 128 + 64 + lane];
      p1[0] = fmaf(a0[kk], w1, p1[0]); p1[1] = fmaf(a1[kk], w1, p1[1]); p1[2] = fmaf(a2[kk], w1, p1[2]);
      p2[0] = fmaf(a0[kk], w2, p2[0]); p2[1] = fmaf(a1[kk], w2, p2[1]); p2[2] = fmaf(a2[kk], w2, p2[2]);
    }
  }

  // ns1/ns2 = silu(n_es @ W_nsp + b_nsp) split
  float s1a = 0.0f, s2a = 0.0f;
  for (int k = 0; k < 64; k += 4) {
    float a[4];
    ld4(S + 3 * 68 + k, a);
    #pragma unroll
    for (int kk = 0; kk < 4; ++kk) {
      s1a = fmaf(a[kk], W_nsp[(k + kk) * 128 + lane], s1a);
      s2a = fmaf(a[kk], W_nsp[(k + kk) * 128 + 64 + lane], s2a);
    }
  }
  float s1 = silu_f(s1a + b_nsp[lane]);
  float s2 = silu_f(s2a + b_nsp[64 + lane]);

  float nvdot = p1[0] * p2[0] + p1[1] * p2[1] + p1[2] * p2[2];
  float nsu = nvdot * s1 + s2;

  // LayerNorm over 64 features (wave-wide)
  float xs = nsu + node_s[n * 64 + lane];
  float sum = xs, sumsq = xs * xs;
  #pragma unroll
  for (int o = 32; o; o >>= 1) {
    sum += __shfl_xor(sum, o);
    sumsq += __shfl_xor(sumsq, o);
  }
  float mu = sum * (1.0f / 64.0f);
  float var = sumsq * (1.0f / 64.0f) - mu * mu;
  ns_out[n * 64 + lane] = (xs - mu) * rsqrtf(var + 1e-5f) * ln_g[lane] + ln_b[lane];

  // CoorsNorm over 3D axis (lane-local)
  float vv[3];
  #pragma unroll
  for (int dd = 0; dd < 3; ++dd) vv[dd] = nvu[dd] + node_v[n * 192 + dd * 64 + lane];
  float vn2 = sqrtf(vv[0] * vv[0] + vv[1] * vv[1] + vv[2] * vv[2]);
  float scale = cn_s[lane] / fmaxf(vn2, 1e-8f);
  #pragma unroll
  for (int dd = 0; dd < 3; ++dd)
    nv_out[n * 192 + dd * 64 + lane] = vv[dd] * scale;
}

extern "C" void kernel_launch(void* const* d_in, const int* in_sizes, int n_in,
                              void* d_out, int out_size, void* d_ws, size_t ws_size,
                              hipStream_t stream) {
  const float* node_s = (const float*)d_in[0];
  const float* node_v = (const float*)d_in[1];
  const float* edge_s = (const float*)d_in[2];
  const float* edge_v = (const float*)d_in[3];
  const float* dist   = (const float*)d_in[4];
  const float* vctr   = (const float*)d_in[5];
  const int*   src    = (const int*)d_in[6];
  const int*   dst    = (const int*)d_in[7];
  const float* W_nn = (const float*)d_in[8];  const float* b_nn = (const float*)d_in[9];
  const float* W_ep = (const float*)d_in[10]; const float* b_ep = (const float*)d_in[11];
  const float* W_g1 = (const float*)d_in[12]; const float* b_g1 = (const float*)d_in[13];
  const float* W_g2 = (const float*)d_in[14]; const float* b_g2 = (const float*)d_in[15];
  const float* W_ev = (const float*)d_in[16]; const float* b_ev = (const float*)d_in[17];
  const float* W_nvout = (const float*)d_in[18];
  const float* W_nvc = (const float*)d_in[19]; const float* b_nvc = (const float*)d_in[20];
  const float* W_nvp = (const float*)d_in[21];
  const float* W_nsp = (const float*)d_in[22]; const float* b_nsp = (const float*)d_in[23];
  const float* ln_g = (const float*)d_in[24]; const float* ln_b = (const float*)d_in[25];
  const float* cn_s = (const float*)d_in[26];

  const int N = in_sizes[0] / 64;
  const int E = in_sizes[2] / 64;

  float* out    = (float*)d_out;
  float* ns_out = out;
  float* nv_out = out + (size_t)N * 64;
  float* es_out = out + (size_t)N * 256;
  float* ev_out = out + (size_t)N * 256 + (size_t)E * 64;

  // ws: CSR ints, then bf16 transposed weights
  int* cnt      = (int*)d_ws;          // N
  int* rowstart = cnt + N;             // N+1
  int* elist    = rowstart + N + 1;    // E
  unsigned short* wnn_t = (unsigned short*)(elist + E);  // 64 x 128
  unsigned short* wep_t = wnn_t + 64 * 128;              // 64 x 64
  unsigned short* wg1_t = wep_t + 64 * 64;
  unsigned short* wg2_t = wg1_t + 64 * 64;
  unsigned short* wev_t = wg2_t + 64 * 64;               // 192 x 64

  hipMemsetAsync(cnt, 0, (size_t)N * sizeof(int), stream);
  hist_kernel<<<(E + 255) / 256, 256, 0, stream>>>(dst, cnt, E);
  scan_kernel<<<1, 1024, 0, stream>>>(cnt, rowstart, N);
  scatter_kernel<<<(E + 255) / 256, 256, 0, stream>>>(dst, cnt, elist, E);

  wprep_kernel<<<(64 * 128 + 255) / 256, 256, 0, stream>>>(W_nn, wnn_t, 128, 64);
  wprep_kernel<<<(64 * 64 + 255) / 256, 256, 0, stream>>>(W_ep, wep_t, 64, 64);
  wprep_kernel<<<(64 * 64 + 255) / 256, 256, 0, stream>>>(W_g1, wg1_t, 64, 64);
  wprep_kernel<<<(64 * 64 + 255) / 256, 256, 0, stream>>>(W_g2, wg2_t, 64, 64);
  wprep_kernel<<<(192 * 64 + 255) / 256, 256, 0, stream>>>(W_ev, wev_t, 64, 192);

  int n_tiles = (E + 15) / 16;
  edge_kernel<<<(n_tiles + 3) / 4, 256, 0, stream>>>(
      node_s, node_v, edge_s, edge_v, dist, vctr, src, dst,
      wnn_t, b_nn, wep_t, b_ep, wg1_t, b_g1, wg2_t, b_g2, wev_t, b_ev,
      es_out, ev_out, E, n_tiles);

  node_kernel<<<(N + 3) / 4, 256, 0, stream>>>(
      node_s, node_v, edge_s, edge_v, es_out, ev_out, rowstart, elist,
      W_nvout, W_nvc, b_nvc, W_nvp, W_nsp, b_nsp,
      ln_g, ln_b, cn_s, ns_out, nv_out, N);
}